// Round 1
// baseline (117.884 us; speedup 1.0000x reference)
//
#include <hip/hip_runtime.h>
#include <stdint.h>

#define D_M   1024
#define L_OBS 2048
#define ALPHA 8192
#define D_H   2048

typedef __attribute__((ext_vector_type(8))) short short8;
typedef __attribute__((ext_vector_type(4))) float f32x4;

__device__ inline unsigned short f2bf(float f) {
  union { float f; unsigned u; } c; c.f = f;
  unsigned u = c.u;
  u += 0x7fffu + ((u >> 16) & 1u);   // round-to-nearest-even
  return (unsigned short)(u >> 16);
}

// ---------------- Kernel 1: scatter + forward-fill, one row per block --------
// Builds regular[m][a] and stores it transposed+bf16 as regT[a][m]
// (K-contiguous layout for the GEMM A operand).
__global__ __launch_bounds__(1024) void impute_fill(
    const float* __restrict__ x_ts, const int* __restrict__ t_ts,
    const float* __restrict__ gmean, unsigned short* __restrict__ regT) {
  __shared__ int   lastl[ALPHA];   // 32 KB: last obs index l that wrote time t, -1 = none
  __shared__ float val[ALPHA];     // 32 KB: winning value at time t
  __shared__ float s_cv[1024];
  __shared__ int   s_ch[1024];

  const int m   = blockIdx.x;
  const int tid = threadIdx.x;

  #pragma unroll
  for (int i = 0; i < 8; ++i) lastl[tid + i * 1024] = -1;
  __syncthreads();

  // scatter pass 1: winner per t = max l (later writes win)
  float xv[2]; int tv[2]; bool vd[2];
  #pragma unroll
  for (int j = 0; j < 2; ++j) {
    const int l = tid + j * 1024;
    xv[j] = x_ts[(size_t)m * L_OBS + l];
    tv[j] = t_ts[(size_t)m * L_OBS + l];
    vd[j] = (xv[j] == xv[j]) && (tv[j] >= 0) && (tv[j] < ALPHA);
    if (vd[j]) atomicMax(&lastl[tv[j]], l);
  }
  __syncthreads();
  // scatter pass 2: unique winner writes its value
  #pragma unroll
  for (int j = 0; j < 2; ++j) {
    const int l = tid + j * 1024;
    if (vd[j] && lastl[tv[j]] == l) val[tv[j]] = xv[j];
  }
  __syncthreads();

  // per-thread chunk of 8 time steps: local (has, last-value) summary
  const int base = tid * 8;
  int has = 0; float lv = 0.f;
  #pragma unroll
  for (int i = 0; i < 8; ++i) {
    const int a = base + i;
    if (lastl[a] >= 0) { has = 1; lv = val[a]; }
  }
  s_ch[tid] = has; s_cv[tid] = lv;
  __syncthreads();
  // Hillis-Steele inclusive scan; combine(L,R) = R.has ? R : L
  for (int off = 1; off < 1024; off <<= 1) {
    int h = 0; float v = 0.f;
    if (tid >= off) { h = s_ch[tid - off]; v = s_cv[tid - off]; }
    __syncthreads();
    if (h && !has) { has = 1; lv = v; }
    s_ch[tid] = has; s_cv[tid] = lv;
    __syncthreads();
  }
  // exclusive carry = inclusive[tid-1]; empty prefix -> global mean
  float running;
  if (tid > 0 && s_ch[tid - 1]) running = s_cv[tid - 1];
  else                          running = gmean[m];
  #pragma unroll
  for (int i = 0; i < 8; ++i) {
    const int a = base + i;
    if (lastl[a] >= 0) running = val[a];
    regT[(size_t)a * D_M + m] = f2bf(running);
  }
}

// ---------------- Kernel 2: W f32 -> bf16 ------------------------------------
__global__ __launch_bounds__(256) void wconv(const float* __restrict__ W,
                                             unsigned short* __restrict__ Wb) {
  const int i = (blockIdx.x * 256 + threadIdx.x) * 4;
  const float4 w = *reinterpret_cast<const float4*>(&W[i]);
  ushort4 o;
  o.x = f2bf(w.x); o.y = f2bf(w.y); o.z = f2bf(w.z); o.w = f2bf(w.w);
  *reinterpret_cast<ushort4*>(&Wb[i]) = o;
}

// ---------------- Kernel 3: bf16 MFMA GEMM + bias ----------------------------
// out[a][h] = sum_m regT[a][m] * Wb[h][m] + b[h]
// M = ALPHA (a), N = D_H (h), K = D_M (m). Both operands K-contiguous.
#define BM 128
#define BN 128
#define BK 64

__device__ inline void gload_lds16(const void* g, void* l) {
  __builtin_amdgcn_global_load_lds(
      (const __attribute__((address_space(1))) unsigned int*)g,
      (__attribute__((address_space(3))) unsigned int*)l, 16, 0, 0);
}

__global__ __launch_bounds__(256) void gemm_bias(
    const unsigned short* __restrict__ A,   // regT [ALPHA][D_M]
    const unsigned short* __restrict__ B,   // Wb   [D_H][D_M]
    const float* __restrict__ bias, float* __restrict__ out) {
  __shared__ unsigned short As[BM][BK];  // 16 KB, k-contiguous rows (128 B)
  __shared__ unsigned short Bs[BN][BK];  // 16 KB

  const int tid  = threadIdx.x;
  const int lane = tid & 63;
  const int wv   = tid >> 6;              // 4 waves: 2x2
  const int wr   = wv >> 1, wc = wv & 1;
  const int bn   = blockIdx.x & (D_H / BN - 1);
  const int bm   = blockIdx.x / (D_H / BN);
  const int a0 = bm * BM, h0 = bn * BN;

  f32x4 acc[4][4] = {};

  // staging: linear 16 KB tile, thread tid covers bytes [i*4096 + tid*16)
  const int  srow  = tid >> 3;            // row within tile (+32 per issue)
  const int  sbyte = (tid & 7) * 16;      // byte offset within 128 B row
  const char* Ab = (const char*)A;
  const char* Bb = (const char*)B;

  for (int kt = 0; kt < D_M / BK; ++kt) {
    const int k0 = kt * BK;
    __syncthreads();                      // prev iter's ds_reads drained here
    #pragma unroll
    for (int i = 0; i < 4; ++i) {
      const int row = i * 32 + srow;
      gload_lds16(Ab + (((size_t)(a0 + row) * D_M + k0) * 2 + sbyte),
                  (char*)As + i * 4096 + tid * 16);
    }
    #pragma unroll
    for (int i = 0; i < 4; ++i) {
      const int row = i * 32 + srow;
      gload_lds16(Bb + (((size_t)(h0 + row) * D_M + k0) * 2 + sbyte),
                  (char*)Bs + i * 4096 + tid * 16);
    }
    asm volatile("s_waitcnt vmcnt(0)" ::: "memory");
    __syncthreads();

    #pragma unroll
    for (int ks = 0; ks < 2; ++ks) {
      short8 af[4], bfr[4];
      const int kk = ks * 32 + (lane >> 4) * 8;
      const int rl = lane & 15;
      #pragma unroll
      for (int f = 0; f < 4; ++f) {
        af[f]  = *(const short8*)&As[wr * 64 + f * 16 + rl][kk];
        bfr[f] = *(const short8*)&Bs[wc * 64 + f * 16 + rl][kk];
      }
      #pragma unroll
      for (int fi = 0; fi < 4; ++fi)
        #pragma unroll
        for (int fj = 0; fj < 4; ++fj)
          acc[fi][fj] = __builtin_amdgcn_mfma_f32_16x16x32_bf16(
              af[fi], bfr[fj], acc[fi][fj], 0, 0, 0);
    }
  }

  // epilogue: D row = (lane>>4)*4 + reg, col = lane&15  [m89-verified]
  const int cl = lane & 15, rlq = lane >> 4;
  #pragma unroll
  for (int fj = 0; fj < 4; ++fj) {
    const int h = h0 + wc * 64 + fj * 16 + cl;
    const float bv = bias[h];
    #pragma unroll
    for (int fi = 0; fi < 4; ++fi) {
      const int ar = a0 + wr * 64 + fi * 16 + rlq * 4;
      #pragma unroll
      for (int r = 0; r < 4; ++r)
        out[(size_t)(ar + r) * D_H + h] = acc[fi][fj][r] + bv;
    }
  }
}

extern "C" void kernel_launch(void* const* d_in, const int* in_sizes, int n_in,
                              void* d_out, int out_size, void* d_ws, size_t ws_size,
                              hipStream_t stream) {
  const float* x  = (const float*)d_in[0];
  const int*   t  = (const int*)d_in[1];
  const float* gm = (const float*)d_in[2];
  const float* W  = (const float*)d_in[3];
  const float* b  = (const float*)d_in[4];
  float* out = (float*)d_out;

  unsigned short* regT = (unsigned short*)d_ws;                         // 16 MB
  unsigned short* Wb   = (unsigned short*)((char*)d_ws +
                          (size_t)ALPHA * D_M * sizeof(unsigned short)); // +4 MB

  impute_fill<<<D_M, 1024, 0, stream>>>(x, t, gm, regT);
  wconv<<<(D_H * D_M) / 1024, 256, 0, stream>>>(W, Wb);
  gemm_bias<<<(ALPHA / BM) * (D_H / BN), 256, 0, stream>>>(regT, Wb, b, out);
}

// Round 2
// 76.196 us; speedup vs baseline: 1.5471x; 1.5471x over previous
//
#include <hip/hip_runtime.h>
#include <stdint.h>

#define D_M   1024
#define L_OBS 2048
#define ALPHA 8192
#define D_H   2048

typedef __attribute__((ext_vector_type(8))) short short8;
typedef __attribute__((ext_vector_type(4))) float f32x4;

__device__ inline unsigned short f2bf(float f) {
  union { float f; unsigned u; } c; c.f = f;
  unsigned u = c.u;
  u += 0x7fffu + ((u >> 16) & 1u);   // round-to-nearest-even
  return (unsigned short)(u >> 16);
}

// ---------------- Kernel 1: scatter + forward-fill, one row per block --------
// transposed_out=0: dst = reg[m][a]  (coalesced 16B stores)
// transposed_out=1: dst = regT[a][m] (scattered fallback, ws-tight case)
__global__ __launch_bounds__(1024) void impute_fill(
    const float* __restrict__ x_ts, const int* __restrict__ t_ts,
    const float* __restrict__ gmean, unsigned short* __restrict__ dst,
    int transposed_out) {
  __shared__ int   lastl[ALPHA];   // 32 KB
  __shared__ float val[ALPHA];     // 32 KB
  __shared__ float s_cv[1024];
  __shared__ int   s_ch[1024];

  const int m   = blockIdx.x;
  const int tid = threadIdx.x;

  #pragma unroll
  for (int i = 0; i < 8; ++i) lastl[tid + i * 1024] = -1;
  __syncthreads();

  float xv[2]; int tv[2]; bool vd[2];
  #pragma unroll
  for (int j = 0; j < 2; ++j) {
    const int l = tid + j * 1024;
    xv[j] = x_ts[(size_t)m * L_OBS + l];
    tv[j] = t_ts[(size_t)m * L_OBS + l];
    vd[j] = (xv[j] == xv[j]) && (tv[j] >= 0) && (tv[j] < ALPHA);
    if (vd[j]) atomicMax(&lastl[tv[j]], l);
  }
  __syncthreads();
  #pragma unroll
  for (int j = 0; j < 2; ++j) {
    const int l = tid + j * 1024;
    if (vd[j] && lastl[tv[j]] == l) val[tv[j]] = xv[j];
  }
  __syncthreads();

  const int base = tid * 8;
  int has = 0; float lv = 0.f;
  #pragma unroll
  for (int i = 0; i < 8; ++i) {
    const int a = base + i;
    if (lastl[a] >= 0) { has = 1; lv = val[a]; }
  }
  s_ch[tid] = has; s_cv[tid] = lv;
  __syncthreads();
  for (int off = 1; off < 1024; off <<= 1) {
    int h = 0; float v = 0.f;
    if (tid >= off) { h = s_ch[tid - off]; v = s_cv[tid - off]; }
    __syncthreads();
    if (h && !has) { has = 1; lv = v; }
    s_ch[tid] = has; s_cv[tid] = lv;
    __syncthreads();
  }
  float running;
  if (tid > 0 && s_ch[tid - 1]) running = s_cv[tid - 1];
  else                          running = gmean[m];

  if (transposed_out) {
    #pragma unroll
    for (int i = 0; i < 8; ++i) {
      const int a = base + i;
      if (lastl[a] >= 0) running = val[a];
      dst[(size_t)a * D_M + m] = f2bf(running);
    }
  } else {
    short8 ov;
    #pragma unroll
    for (int i = 0; i < 8; ++i) {
      const int a = base + i;
      if (lastl[a] >= 0) running = val[a];
      ov[i] = (short)f2bf(running);
    }
    *(short8*)&dst[(size_t)m * ALPHA + base] = ov;
  }
}

// ---------------- Kernel 1b: transpose reg[m][a] -> regT[a][m] ---------------
// 64x64 bf16 tiles; XOR-swizzled LDS: elem offset e ^ (((m&7)^(m>>3))<<3)
// -> both global sides 128B-coalesced, LDS ~2-way (free).
__global__ __launch_bounds__(256) void transpose_bf(
    const unsigned short* __restrict__ reg, unsigned short* __restrict__ regT) {
  __shared__ unsigned short tile[64 * 64];
  const int t  = threadIdx.x;
  const int m0 = (blockIdx.x & 15) * 64;    // D_M/64 = 16
  const int A0 = (blockIdx.x >> 4) * 64;    // ALPHA/64 = 128

  #pragma unroll
  for (int i = 0; i < 2; ++i) {
    const int m  = i * 32 + (t >> 3);
    const int ao = (t & 7) * 8;
    short8 v = *(const short8*)&reg[(size_t)(m0 + m) * ALPHA + A0 + ao];
    const int s = ((m & 7) ^ (m >> 3)) << 3;
    *(short8*)&tile[m * 64 + (ao ^ s)] = v;
  }
  __syncthreads();
  #pragma unroll
  for (int i = 0; i < 2; ++i) {
    const int a  = i * 32 + (t >> 3);
    const int mo = (t & 7) * 8;
    short8 ov;
    #pragma unroll
    for (int j = 0; j < 8; ++j) {
      const int mm = mo + j;
      const int s  = ((mm & 7) ^ (mm >> 3)) << 3;
      ov[j] = (short)tile[mm * 64 + (a ^ s)];
    }
    *(short8*)&regT[(size_t)(A0 + a) * D_M + m0 + mo] = ov;
  }
}

// ---------------- Kernel 2: W f32 -> bf16 ------------------------------------
__global__ __launch_bounds__(256) void wconv(const float* __restrict__ W,
                                             unsigned short* __restrict__ Wb) {
  const int i = (blockIdx.x * 256 + threadIdx.x) * 4;
  const float4 w = *reinterpret_cast<const float4*>(&W[i]);
  ushort4 o;
  o.x = f2bf(w.x); o.y = f2bf(w.y); o.z = f2bf(w.z); o.w = f2bf(w.w);
  *reinterpret_cast<ushort4*>(&Wb[i]) = o;
}

// ---------------- Kernel 3: 256x256 MFMA GEMM, 4-deep ring, counted vmcnt ----
// out[a][h] = sum_m regT[a][m] * Wb[h][m] + b[h]
// M=ALPHA, N=D_H, K=D_M. BK=32, 8 waves (2Mx4N), per-wave 128x64.
// LDS: 4 slots x (A 16KB + B 16KB) = 128KB. Stage kt+3 during kt (race-free:
// slot (kt+3)&3 last read in kt-1, separated by kt's boundary barrier).
#define GBM 256
#define GBN 256
#define GBK 32
#define GNT (D_M / GBK)   // 32

__device__ inline void gload_lds16(const void* g, void* l) {
  __builtin_amdgcn_global_load_lds(
      (const __attribute__((address_space(1))) unsigned int*)g,
      (__attribute__((address_space(3))) unsigned int*)l, 16, 0, 0);
}

#define BARX() { asm volatile("" ::: "memory"); __builtin_amdgcn_s_barrier(); \
                 asm volatile("" ::: "memory"); }

__global__ __launch_bounds__(512, 2) void gemm_bias(
    const unsigned short* __restrict__ A,   // regT [ALPHA][D_M]
    const unsigned short* __restrict__ B,   // Wb   [D_H][D_M]
    const float* __restrict__ bias, float* __restrict__ out) {
  __shared__ char lds[4 * 32768];           // slot: A @ s*32768, B @ +16384

  const int tid  = threadIdx.x;
  const int lane = tid & 63;
  const int wid  = tid >> 6;
  const int wm   = wid >> 2;                // 0..1
  const int wn   = wid & 3;                 // 0..3
  const int bn   = blockIdx.x & 7;          // D_H/256 = 8  (XCD = bid%8 = bn)
  const int bm   = blockIdx.x >> 3;
  const int a0 = bm * GBM, h0 = bn * GBN;

  f32x4 acc[8][4] = {};

  // ---- staging addressing: linear LDS dest, inverse-swizzled global source
  // dest byte (within 16KB half): tid*16 (+ i*8192); logical row = i*128+(tid>>2),
  // cb = (tid&3)*16; source col-byte = cb ^ (((row>>1)&3)<<4)  [i-independent]
  const int srow = tid >> 2;
  const int cbp  = ((tid & 3) * 16) ^ (((srow >> 1) & 3) << 4);
  const char* Abase = (const char*)A + ((size_t)(a0 + srow) * D_M) * 2 + cbp;
  const char* Bbase = (const char*)B + ((size_t)(h0 + srow) * D_M) * 2 + cbp;
  const size_t rstep = (size_t)128 * D_M * 2;   // +128 rows

#define STAGE_A(kt) { const int s_ = ((kt) & 3) * 32768; const size_t ko_ = (size_t)(kt) * (GBK*2); \
  gload_lds16(Abase + ko_,         lds + s_ + tid * 16); \
  gload_lds16(Abase + ko_ + rstep, lds + s_ + 8192 + tid * 16); }
#define STAGE_B(kt) { const int s_ = ((kt) & 3) * 32768; const size_t ko_ = (size_t)(kt) * (GBK*2); \
  gload_lds16(Bbase + ko_,         lds + s_ + 16384 + tid * 16); \
  gload_lds16(Bbase + ko_ + rstep, lds + s_ + 16384 + 8192 + tid * 16); }

  // ---- fragment read addressing (same involutive swizzle on the read)
  const int rl   = lane & 15;
  const int kb   = (lane >> 4) * 16;
  const int rswz = ((rl >> 1) & 3) << 4;
  const int aoff = (wm * 128 + rl) * 64 + (kb ^ rswz);          // +mh*4096 +f*1024
  const int boff = 16384 + (wn * 64 + rl) * 64 + (kb ^ rswz);   // +n*1024

  // ---- prologue: 3 K-tiles in flight
  STAGE_A(0); STAGE_B(0); STAGE_A(1); STAGE_B(1); STAGE_A(2); STAGE_B(2);
  asm volatile("s_waitcnt vmcnt(8)" ::: "memory");   // tile 0 landed
  BARX();

  #pragma unroll 4
  for (int kt = 0; kt < GNT; ++kt) {
    const int sb = (kt & 3) * 32768;
    short8 af[4], bf[4];
    // ---- phase 0: read B(all) + A(mh=0), stage A(kt+3), MFMA quadrant 0
    #pragma unroll
    for (int n = 0; n < 4; ++n) bf[n] = *(const short8*)(lds + sb + boff + n * 1024);
    #pragma unroll
    for (int f = 0; f < 4; ++f) af[f] = *(const short8*)(lds + sb + aoff + f * 1024);
    if (kt < GNT - 3) STAGE_A(kt + 3);
    BARX();
    __builtin_amdgcn_s_setprio(1);
    #pragma unroll
    for (int f = 0; f < 4; ++f)
      #pragma unroll
      for (int n = 0; n < 4; ++n)
        acc[f][n] = __builtin_amdgcn_mfma_f32_16x16x32_bf16(af[f], bf[n], acc[f][n], 0, 0, 0);
    __builtin_amdgcn_s_setprio(0);
    BARX();
    // ---- phase 1: read A(mh=1), stage B(kt+3), MFMA quadrant 1
    #pragma unroll
    for (int f = 0; f < 4; ++f) af[f] = *(const short8*)(lds + sb + aoff + 4096 + f * 1024);
    if (kt < GNT - 3) STAGE_B(kt + 3);
    BARX();
    __builtin_amdgcn_s_setprio(1);
    #pragma unroll
    for (int f = 0; f < 4; ++f)
      #pragma unroll
      for (int n = 0; n < 4; ++n)
        acc[4 + f][n] = __builtin_amdgcn_mfma_f32_16x16x32_bf16(af[f], bf[n], acc[4 + f][n], 0, 0, 0);
    __builtin_amdgcn_s_setprio(0);
    // counted drain: keep tiles kt+2, kt+3 in flight; never vmcnt(0) mid-loop
    if (kt < GNT - 3)       { asm volatile("s_waitcnt vmcnt(8)" ::: "memory"); }
    else if (kt == GNT - 3) { asm volatile("s_waitcnt vmcnt(4)" ::: "memory"); }
    else if (kt == GNT - 2) { asm volatile("s_waitcnt vmcnt(0)" ::: "memory"); }
    BARX();
  }

  // ---- epilogue: C row = (lane>>4)*4 + r (A side), col = lane&15 (B side)
  const int cl = lane & 15, rq = lane >> 4;
  #pragma unroll
  for (int n = 0; n < 4; ++n) {
    const int h = h0 + wn * 64 + n * 16 + cl;
    const float bv = bias[h];
    #pragma unroll
    for (int m = 0; m < 8; ++m) {
      const int ar = a0 + wm * 128 + m * 16 + rq * 4;
      #pragma unroll
      for (int r = 0; r < 4; ++r)
        out[(size_t)(ar + r) * D_H + h] = acc[m][n][r] + bv;
    }
  }
#undef STAGE_A
#undef STAGE_B
}

extern "C" void kernel_launch(void* const* d_in, const int* in_sizes, int n_in,
                              void* d_out, int out_size, void* d_ws, size_t ws_size,
                              hipStream_t stream) {
  const float* x  = (const float*)d_in[0];
  const int*   t  = (const int*)d_in[1];
  const float* gm = (const float*)d_in[2];
  const float* W  = (const float*)d_in[3];
  const float* b  = (const float*)d_in[4];
  float* out = (float*)d_out;

  const size_t SZ_REG = (size_t)ALPHA * D_M * 2;   // 16 MB
  const size_t SZ_WB  = (size_t)D_H * D_M * 2;     //  4 MB

  if (ws_size >= 2 * SZ_REG + SZ_WB) {
    unsigned short* reg  = (unsigned short*)d_ws;
    unsigned short* regT = (unsigned short*)((char*)d_ws + SZ_REG);
    unsigned short* Wb   = (unsigned short*)((char*)d_ws + 2 * SZ_REG);
    impute_fill<<<D_M, 1024, 0, stream>>>(x, t, gm, reg, 0);
    wconv<<<(D_H * D_M) / 1024, 256, 0, stream>>>(W, Wb);
    transpose_bf<<<(ALPHA / 64) * (D_M / 64), 256, 0, stream>>>(reg, regT);
    gemm_bias<<<(ALPHA / GBM) * (D_H / GBN), 512, 0, stream>>>(regT, Wb, b, out);
  } else {
    unsigned short* regT = (unsigned short*)d_ws;
    unsigned short* Wb   = (unsigned short*)((char*)d_ws + SZ_REG);
    impute_fill<<<D_M, 1024, 0, stream>>>(x, t, gm, regT, 1);
    wconv<<<(D_H * D_M) / 1024, 256, 0, stream>>>(W, Wb);
    gemm_bias<<<(ALPHA / GBM) * (D_H / GBN), 512, 0, stream>>>(regT, Wb, b, out);
  }
}

// Round 4
// 66.930 us; speedup vs baseline: 1.7613x; 1.1384x over previous
//
#include <hip/hip_runtime.h>
#include <stdint.h>

#define D_M   1024
#define L_OBS 2048
#define ALPHA 8192
#define D_H   2048

typedef __attribute__((ext_vector_type(8))) short short8;
typedef __attribute__((ext_vector_type(4))) float f32x4;

__device__ inline unsigned short f2bf(float f) {
  union { float f; unsigned u; } c; c.f = f;
  unsigned u = c.u;
  u += 0x7fffu + ((u >> 16) & 1u);   // round-to-nearest-even
  return (unsigned short)(u >> 16);
}

// ---------------- Kernel 1: scatter + forward-fill, one row per block --------
// Packed scatter: LDS atomicMax of ((l+1)<<32 | bits(x)) -> later l wins and
// carries its value; forward-fill via 2-level shuffle scan (4 barriers total).
__global__ __launch_bounds__(1024) void impute_fill(
    const float* __restrict__ x_ts, const int* __restrict__ t_ts,
    const float* __restrict__ gmean, unsigned short* __restrict__ dst,
    int transposed_out) {
  __shared__ unsigned long long pack[ALPHA];   // 64 KB; 0 = no observation
  __shared__ float s_wv[16];
  __shared__ int   s_wh[16];

  const int m    = blockIdx.x;
  const int tid  = threadIdx.x;
  const int lane = tid & 63;
  const int wv   = tid >> 6;

  #pragma unroll
  for (int i = 0; i < 8; ++i) pack[tid + i * 1024] = 0ull;
  __syncthreads();

  #pragma unroll
  for (int j = 0; j < 2; ++j) {
    const int l = tid + j * 1024;
    const float xv = x_ts[(size_t)m * L_OBS + l];
    const int   tv = t_ts[(size_t)m * L_OBS + l];
    if ((xv == xv) && (tv >= 0) && (tv < ALPHA)) {
      union { float f; unsigned u; } c; c.f = xv;
      atomicMax(&pack[tv], ((unsigned long long)(l + 1) << 32) | c.u);
    }
  }
  __syncthreads();

  // per-thread chunk of 8 time steps: (has, last-value) summary
  const int base = tid * 8;
  int has = 0; float lv = 0.f;
  #pragma unroll
  for (int i = 0; i < 8; ++i) {
    const unsigned long long p = pack[base + i];
    if (p >> 32) { has = 1; lv = __uint_as_float((unsigned)p); }
  }

  // wave-level inclusive scan, combine(L,R) = R.has ? R : L
  int ihas = has; float ilv = lv;
  #pragma unroll
  for (int d = 1; d < 64; d <<= 1) {
    const float pv = __shfl_up(ilv, d, 64);
    const int   ph = __shfl_up(ihas, d, 64);
    if (lane >= d && !ihas) { ihas = ph; ilv = pv; }
  }
  if (lane == 63) { s_wh[wv] = ihas; s_wv[wv] = ilv; }
  __syncthreads();
  // wave 0 scans the 16 wave summaries (inclusive)
  if (wv == 0 && lane < 16) {
    int h2 = s_wh[lane]; float v2 = s_wv[lane];
    #pragma unroll
    for (int d = 1; d < 16; d <<= 1) {
      const float pv = __shfl_up(v2, d, 16);
      const int   ph = __shfl_up(h2, d, 16);
      if (lane >= d && !h2) { h2 = ph; v2 = pv; }
    }
    s_wh[lane] = h2; s_wv[lane] = v2;
  }
  __syncthreads();

  // exclusive carry for this thread
  const float xlv = __shfl_up(ilv, 1, 64);
  const int   xh_ = __shfl_up(ihas, 1, 64);
  const int   xhas = (lane > 0) ? xh_ : 0;
  float running;
  if (xhas)                         running = xlv;
  else if (wv > 0 && s_wh[wv - 1])  running = s_wv[wv - 1];
  else                              running = gmean[m];

  if (transposed_out) {
    #pragma unroll
    for (int i = 0; i < 8; ++i) {
      const unsigned long long p = pack[base + i];
      if (p >> 32) running = __uint_as_float((unsigned)p);
      dst[(size_t)(base + i) * D_M + m] = f2bf(running);
    }
  } else {
    short8 ov;
    #pragma unroll
    for (int i = 0; i < 8; ++i) {
      const unsigned long long p = pack[base + i];
      if (p >> 32) running = __uint_as_float((unsigned)p);
      ov[i] = (short)f2bf(running);
    }
    *(short8*)&dst[(size_t)m * ALPHA + base] = ov;
  }
}

// ---------------- Kernel 1b: transpose reg[m][a] -> regT[a][m] ---------------
__global__ __launch_bounds__(256) void transpose_bf(
    const unsigned short* __restrict__ reg, unsigned short* __restrict__ regT) {
  __shared__ unsigned short tile[64 * 64];
  const int t  = threadIdx.x;
  const int m0 = (blockIdx.x & 15) * 64;
  const int A0 = (blockIdx.x >> 4) * 64;

  #pragma unroll
  for (int i = 0; i < 2; ++i) {
    const int m  = i * 32 + (t >> 3);
    const int ao = (t & 7) * 8;
    short8 v = *(const short8*)&reg[(size_t)(m0 + m) * ALPHA + A0 + ao];
    const int s = ((m & 7) ^ (m >> 3)) << 3;
    *(short8*)&tile[m * 64 + (ao ^ s)] = v;
  }
  __syncthreads();
  #pragma unroll
  for (int i = 0; i < 2; ++i) {
    const int a  = i * 32 + (t >> 3);
    const int mo = (t & 7) * 8;
    short8 ov;
    #pragma unroll
    for (int j = 0; j < 8; ++j) {
      const int mm = mo + j;
      const int s  = ((mm & 7) ^ (mm >> 3)) << 3;
      ov[j] = (short)tile[mm * 64 + (a ^ s)];
    }
    *(short8*)&regT[(size_t)(A0 + a) * D_M + m0 + mo] = ov;
  }
}

// ---------------- Kernel 2: W f32 -> bf16 ------------------------------------
__global__ __launch_bounds__(256) void wconv(const float* __restrict__ W,
                                             unsigned short* __restrict__ Wb) {
  const int i = (blockIdx.x * 256 + threadIdx.x) * 4;
  const float4 w = *reinterpret_cast<const float4*>(&W[i]);
  ushort4 o;
  o.x = f2bf(w.x); o.y = f2bf(w.y); o.z = f2bf(w.z); o.w = f2bf(w.w);
  *reinterpret_cast<ushort4*>(&Wb[i]) = o;
}

// ---------------- Kernel 3: 256x256 MFMA GEMM, 1 barrier / K-tile ------------
// out[a][h] = sum_m regT[a][m] * Wb[h][m] + b[h]
// BK=32, 8 waves (2Mx4N), per-wave 128x64. LDS: 4-slot ring x 32KB = 128KB.
// Per tile: 12 ds_read_b128 + stage(kt+3) + 32 MFMA (compiler-interleaved via
// fine lgkmcnt) + vmcnt(8) + ONE raw s_barrier. Race-free: slot(kt+3) =
// slot(kt-1), last read before barrier(kt-1); per-wave vmcnt before barrier
// makes all waves' kt+1 loads LDS-visible after it.
#define GBM 256
#define GBN 256
#define GBK 32
#define GNT (D_M / GBK)   // 32

__device__ inline void gload_lds16(const void* g, void* l) {
  __builtin_amdgcn_global_load_lds(
      (const __attribute__((address_space(1))) unsigned int*)g,
      (__attribute__((address_space(3))) unsigned int*)l, 16, 0, 0);
}

#define BARX() { asm volatile("" ::: "memory"); __builtin_amdgcn_s_barrier(); \
                 asm volatile("" ::: "memory"); }

__global__ __launch_bounds__(512, 2) void gemm_bias(
    const unsigned short* __restrict__ A,   // regT [ALPHA][D_M]
    const unsigned short* __restrict__ B,   // Wb   [D_H][D_M]
    const float* __restrict__ bias, float* __restrict__ out) {
  __shared__ char lds[4 * 32768];           // slot: A @ s*32768, B @ +16384

  const int tid  = threadIdx.x;
  const int lane = tid & 63;
  const int wid  = tid >> 6;
  const int wm   = wid >> 2;                // 0..1
  const int wn   = wid & 3;                 // 0..3
  const int bn   = blockIdx.x & 7;          // XCD-local B panel (bid%8 = xcd)
  const int bm   = blockIdx.x >> 3;
  const int a0 = bm * GBM, h0 = bn * GBN;

  f32x4 acc[8][4] = {};

  // staging: linear LDS dest, inverse-swizzled global source (R2-verified, 0 conflicts)
  const int srow = tid >> 2;
  const int cbp  = ((tid & 3) * 16) ^ (((srow >> 1) & 3) << 4);
  const char* Abase = (const char*)A + ((size_t)(a0 + srow) * D_M) * 2 + cbp;
  const char* Bbase = (const char*)B + ((size_t)(h0 + srow) * D_M) * 2 + cbp;
  const size_t rstep = (size_t)128 * D_M * 2;

#define STAGE_A(kt) { const int s_ = ((kt) & 3) * 32768; const size_t ko_ = (size_t)(kt) * (GBK*2); \
  gload_lds16(Abase + ko_,         lds + s_ + tid * 16); \
  gload_lds16(Abase + ko_ + rstep, lds + s_ + 8192 + tid * 16); }
#define STAGE_B(kt) { const int s_ = ((kt) & 3) * 32768; const size_t ko_ = (size_t)(kt) * (GBK*2); \
  gload_lds16(Bbase + ko_,         lds + s_ + 16384 + tid * 16); \
  gload_lds16(Bbase + ko_ + rstep, lds + s_ + 16384 + 8192 + tid * 16); }

  // fragment read addressing (involutive swizzle on the read side)
  const int rl   = lane & 15;
  const int kb   = (lane >> 4) * 16;
  const int rswz = ((rl >> 1) & 3) << 4;
  const int aoff = (wm * 128 + rl) * 64 + (kb ^ rswz);          // + f*1024
  const int boff = 16384 + (wn * 64 + rl) * 64 + (kb ^ rswz);   // + n*1024

  // prologue: 3 K-tiles in flight
  STAGE_A(0); STAGE_B(0); STAGE_A(1); STAGE_B(1); STAGE_A(2); STAGE_B(2);
  asm volatile("s_waitcnt vmcnt(8)" ::: "memory");   // tile 0 landed (per-wave)
  BARX();

  #pragma unroll 4
  for (int kt = 0; kt < GNT; ++kt) {
    const int sb = (kt & 3) * 32768;
    short8 af[8], bf[4];
    #pragma unroll
    for (int n = 0; n < 4; ++n) bf[n] = *(const short8*)(lds + sb + boff + n * 1024);
    #pragma unroll
    for (int f = 0; f < 8; ++f) af[f] = *(const short8*)(lds + sb + aoff + f * 1024);
    if (kt < GNT - 3) { STAGE_A(kt + 3); STAGE_B(kt + 3); }
    __builtin_amdgcn_s_setprio(1);
    #pragma unroll
    for (int f = 0; f < 8; ++f)
      #pragma unroll
      for (int n = 0; n < 4; ++n)
        acc[f][n] = __builtin_amdgcn_mfma_f32_16x16x32_bf16(af[f], bf[n], acc[f][n], 0, 0, 0);
    __builtin_amdgcn_s_setprio(0);
    // counted drain: ensure kt+1 landed; keep kt+2, kt+3 (8 loads) in flight
    if (kt < GNT - 3)       { asm volatile("s_waitcnt vmcnt(8)" ::: "memory"); }
    else if (kt == GNT - 3) { asm volatile("s_waitcnt vmcnt(4)" ::: "memory"); }
    else if (kt == GNT - 2) { asm volatile("s_waitcnt vmcnt(0)" ::: "memory"); }
    BARX();
  }

  // epilogue: C row = (lane>>4)*4 + r (A side), col = lane&15 (B side)
  const int cl = lane & 15, rq = lane >> 4;
  #pragma unroll
  for (int n = 0; n < 4; ++n) {
    const int h = h0 + wn * 64 + n * 16 + cl;
    const float bv = bias[h];
    #pragma unroll
    for (int f = 0; f < 8; ++f) {
      const int ar = a0 + wm * 128 + f * 16 + rq * 4;
      #pragma unroll
      for (int r = 0; r < 4; ++r)
        out[(size_t)(ar + r) * D_H + h] = acc[f][n][r] + bv;
    }
  }
#undef STAGE_A
#undef STAGE_B
}

extern "C" void kernel_launch(void* const* d_in, const int* in_sizes, int n_in,
                              void* d_out, int out_size, void* d_ws, size_t ws_size,
                              hipStream_t stream) {
  const float* x  = (const float*)d_in[0];
  const int*   t  = (const int*)d_in[1];
  const float* gm = (const float*)d_in[2];
  const float* W  = (const float*)d_in[3];
  const float* b  = (const float*)d_in[4];
  float* out = (float*)d_out;

  const size_t SZ_REG = (size_t)ALPHA * D_M * 2;   // 16 MB
  const size_t SZ_WB  = (size_t)D_H * D_M * 2;     //  4 MB

  if (ws_size >= 2 * SZ_REG + SZ_WB) {
    unsigned short* reg  = (unsigned short*)d_ws;
    unsigned short* regT = (unsigned short*)((char*)d_ws + SZ_REG);
    unsigned short* Wb   = (unsigned short*)((char*)d_ws + 2 * SZ_REG);
    impute_fill<<<D_M, 1024, 0, stream>>>(x, t, gm, reg, 0);
    wconv<<<(D_H * D_M) / 1024, 256, 0, stream>>>(W, Wb);
    transpose_bf<<<(ALPHA / 64) * (D_M / 64), 256, 0, stream>>>(reg, regT);
    gemm_bias<<<(ALPHA / GBM) * (D_H / GBN), 512, 0, stream>>>(regT, Wb, b, out);
  } else {
    unsigned short* regT = (unsigned short*)d_ws;
    unsigned short* Wb   = (unsigned short*)((char*)d_ws + SZ_REG);
    impute_fill<<<D_M, 1024, 0, stream>>>(x, t, gm, regT, 1);
    wconv<<<(D_H * D_M) / 1024, 256, 0, stream>>>(W, Wb);
    gemm_bias<<<(ALPHA / GBM) * (D_H / GBN), 512, 0, stream>>>(regT, Wb, b, out);
  }
}